// Round 6
// baseline (695.937 us; speedup 1.0000x reference)
//
#include <hip/hip_runtime.h>
#include <hip/hip_bf16.h>

#define N_    64
#define T_    32
#define H_    64
#define W_    64
#define C_    256
#define HID   512
#define HID4  2048
#define NBLK  12
#define P_    7
#define OUT_  388
#define OUTP  448      // OUT_ padded to 64
#define CIN   51
#define M_    (N_*T_)   // 2048

typedef __attribute__((ext_vector_type(4))) float f32x4;
typedef __attribute__((ext_vector_type(8))) short bf16x8;

__device__ __forceinline__ float gelu_f(float x) {
    float x3 = x * x * x;
    return 0.5f * x * (1.f + tanhf(0.7978845608028654f * (x + 0.044715f * x3)));
}

__device__ __forceinline__ void gload_lds16(const void* g, void* l) {
    __builtin_amdgcn_global_load_lds(
        (const __attribute__((address_space(1))) void*)g,
        (__attribute__((address_space(3))) void*)l, 16, 0, 0);
}

// ---------------------------------------------------------------------------
// Patch extraction + input projection fused (unchanged)
// ---------------------------------------------------------------------------
__global__ __launch_bounds__(256) void patch_kernel(
    const float* __restrict__ fg, const float* __restrict__ qf,
    const float* __restrict__ pos, const float* __restrict__ in_w,
    const float* __restrict__ in_b, float* __restrict__ x) {
    __shared__ float4 q[64];
    __shared__ float g[8][8];
    __shared__ float xrow[CIN];
    int m = blockIdx.x;
    int n = m >> 5;
    int t = m & (T_ - 1);
    int tid = threadIdx.x, wid = tid >> 6, lane = tid & 63;
    if (tid < 64) q[tid] = *(const float4*)&qf[n * C_ + tid * 4];
    __syncthreads();
    float posy = pos[m * 2 + 0];
    float posx = pos[m * 2 + 1];
    float py = posy + 2.5f;
    float px = posx + 2.5f;
    int iy = (int)floorf(py), ix = (int)floorf(px);
    float fy = py - (float)iy, fx = px - (float)ix;
    float4 qv = q[lane];
    #pragma unroll
    for (int i = 0; i < 16; ++i) {
        int idx = wid * 16 + i;
        int a = idx >> 3, b = idx & 7;
        int y = iy + a - 6, xc = ix + b - 6;
        float partial = 0.f;
        if (y >= 0 && y < H_ && xc >= 0 && xc < W_) {
            const float4* fp = (const float4*)&fg[(((t * H_ + y) * W_) + xc) * C_];
            float4 v = fp[lane];
            partial = v.x * qv.x + v.y * qv.y + v.z * qv.z + v.w * qv.w;
        }
        #pragma unroll
        for (int o2 = 32; o2; o2 >>= 1) partial += __shfl_xor(partial, o2);
        if (lane == 0) g[a][b] = partial;
    }
    __syncthreads();
    if (tid < 49) {
        int p = tid / 7, qq = tid % 7;
        xrow[tid] = (1.f - fy) * (1.f - fx) * g[p][qq]
                  + (1.f - fy) * fx         * g[p][qq + 1]
                  + fy         * (1.f - fx) * g[p + 1][qq]
                  + fy         * fx         * g[p + 1][qq + 1];
    } else if (tid == 49) {
        xrow[49] = posy * (1.f / 64.f);
    } else if (tid == 50) {
        xrow[50] = posx * (1.f / 64.f);
    }
    __syncthreads();
    float acc0 = in_b[tid], acc1 = in_b[tid + 256];
    #pragma unroll
    for (int c = 0; c < CIN; ++c) {
        float rv = xrow[c];
        acc0 += rv * in_w[c * HID + tid];
        acc1 += rv * in_w[c * HID + tid + 256];
    }
    x[m * HID + tid] = acc0;
    x[m * HID + tid + 256] = acc1;
}

// ---------------------------------------------------------------------------
// Fully fused depthwise residual block + ln2 (unchanged)
// ---------------------------------------------------------------------------
__global__ __launch_bounds__(512) void fused_dw_kernel(
    const float* __restrict__ xin, float* __restrict__ xout,
    __hip_bfloat16* __restrict__ t1b,
    const float* __restrict__ ln1s, const float* __restrict__ ln2s,
    const float* __restrict__ w1, const float* __restrict__ b1,
    const float* __restrict__ w2, const float* __restrict__ b2) {
    __shared__ float2 part[12][8];
    int n = blockIdx.y;
    int t0 = blockIdx.x * 8;
    int j = threadIdx.x;
    int lane = j & 63, wave = j >> 6;

    float xv[12];
    #pragma unroll
    for (int tt = 0; tt < 12; ++tt) {
        int t = t0 - 2 + tt;
        xv[tt] = (t >= 0 && t < T_) ? xin[(n * T_ + t) * HID + j] : 0.f;
    }
    #pragma unroll
    for (int tt = 0; tt < 12; ++tt) {
        float s = xv[tt], q = xv[tt] * xv[tt];
        #pragma unroll
        for (int o = 32; o; o >>= 1) { s += __shfl_xor(s, o); q += __shfl_xor(q, o); }
        if (lane == 0) part[tt][wave] = make_float2(s, q);
    }
    __syncthreads();
    float s1v = ln1s[j];
    float xl[12];
    #pragma unroll
    for (int tt = 0; tt < 12; ++tt) {
        int t = t0 - 2 + tt;
        if (t >= 0 && t < T_) {
            float s = 0.f, q = 0.f;
            #pragma unroll
            for (int w = 0; w < 8; ++w) { float2 p = part[tt][w]; s += p.x; q += p.y; }
            float mean = s * (1.f / HID);
            float var  = q * (1.f / HID) - mean * mean;
            xl[tt] = (xv[tt] - mean) * rsqrtf(var + 1e-5f) * s1v;
        } else xl[tt] = 0.f;
    }
    float w1a[12], w2a[12], b1a[4];
    #pragma unroll
    for (int r = 0; r < 3; ++r) {
        *(float4*)&w1a[r * 4] = *(const float4*)&w1[r * HID4 + 4 * j];
        *(float4*)&w2a[r * 4] = *(const float4*)&w2[r * HID4 + 4 * j];
    }
    *(float4*)&b1a[0] = *(const float4*)&b1[4 * j];
    float4 b2v = *(const float4*)&b2[4 * j];
    float h[8];
    float b2sum = b2v.x + b2v.y + b2v.z + b2v.w;
    #pragma unroll
    for (int i = 0; i < 8; ++i) h[i] = b2sum;
    #pragma unroll
    for (int k = 0; k < 4; ++k) {
        float gk[10];
        #pragma unroll
        for (int idx = 0; idx < 10; ++idx) {
            int tp = t0 - 1 + idx;
            if (tp >= 0 && tp < T_) {
                float a = b1a[k] + w1a[0 * 4 + k] * xl[idx]
                                 + w1a[1 * 4 + k] * xl[idx + 1]
                                 + w1a[2 * 4 + k] * xl[idx + 2];
                gk[idx] = gelu_f(a);
            } else gk[idx] = 0.f;
        }
        #pragma unroll
        for (int i = 0; i < 8; ++i)
            h[i] += w2a[0 * 4 + k] * gk[i] + w2a[1 * 4 + k] * gk[i + 1]
                  + w2a[2 * 4 + k] * gk[i + 2];
    }
    float xn[8];
    #pragma unroll
    for (int i = 0; i < 8; ++i) xn[i] = xv[i + 2] + h[i];
    __syncthreads();
    #pragma unroll
    for (int i = 0; i < 8; ++i) {
        float s = xn[i], q = xn[i] * xn[i];
        #pragma unroll
        for (int o = 32; o; o >>= 1) { s += __shfl_xor(s, o); q += __shfl_xor(q, o); }
        if (lane == 0) part[i][wave] = make_float2(s, q);
    }
    __syncthreads();
    float s2v = ln2s[j];
    #pragma unroll
    for (int i = 0; i < 8; ++i) {
        float s = 0.f, q = 0.f;
        #pragma unroll
        for (int w = 0; w < 8; ++w) { float2 p = part[i][w]; s += p.x; q += p.y; }
        float mean = s * (1.f / HID);
        float var  = q * (1.f / HID) - mean * mean;
        float rstd = rsqrtf(var + 1e-5f);
        int m = (n * T_ + t0 + i) * HID + j;
        xout[m] = xn[i];
        t1b[m] = __float2bfloat16((xn[i] - mean) * rstd * s2v);
    }
}

// ---------------------------------------------------------------------------
// LayerNorm bf16-out (final LN only, unchanged)
// ---------------------------------------------------------------------------
__global__ __launch_bounds__(256) void ln_kernel(
    const float* __restrict__ in, const float* __restrict__ s,
    __hip_bfloat16* __restrict__ outb) {
    int wid = threadIdx.x >> 6, lane = threadIdx.x & 63;
    int row = blockIdx.x * 4 + wid;
    const float* r = in + row * HID + lane * 8;
    float4 v0 = *(const float4*)r;
    float4 v1 = *(const float4*)(r + 4);
    float sum = v0.x + v0.y + v0.z + v0.w + v1.x + v1.y + v1.z + v1.w;
    float sq  = v0.x*v0.x + v0.y*v0.y + v0.z*v0.z + v0.w*v0.w
              + v1.x*v1.x + v1.y*v1.y + v1.z*v1.z + v1.w*v1.w;
    #pragma unroll
    for (int o = 32; o; o >>= 1) { sum += __shfl_xor(sum, o); sq += __shfl_xor(sq, o); }
    float mean = sum * (1.f / HID);
    float var  = sq * (1.f / HID) - mean * mean;
    float rstd = rsqrtf(var + 1e-5f);
    const float* sp = s + lane * 8;
    float4 s0 = *(const float4*)sp;
    float4 s1 = *(const float4*)(sp + 4);
    float o[8];
    o[0] = (v0.x - mean) * rstd * s0.x; o[1] = (v0.y - mean) * rstd * s0.y;
    o[2] = (v0.z - mean) * rstd * s0.z; o[3] = (v0.w - mean) * rstd * s0.w;
    o[4] = (v1.x - mean) * rstd * s1.x; o[5] = (v1.y - mean) * rstd * s1.y;
    o[6] = (v1.z - mean) * rstd * s1.z; o[7] = (v1.w - mean) * rstd * s1.w;
    alignas(16) __hip_bfloat16 tmp[8];
    #pragma unroll
    for (int i = 0; i < 8; ++i) tmp[i] = __float2bfloat16(o[i]);
    *(bf16x8*)&outb[row * HID + lane * 8] = *(bf16x8*)tmp;
}

// ---------------------------------------------------------------------------
// Transpose + fp32 -> bf16 convert (weights, unchanged)
// ---------------------------------------------------------------------------
__global__ __launch_bounds__(256) void tcvt_kernel(
    const float* __restrict__ src, __hip_bfloat16* __restrict__ dst,
    int R, int C, int Cpad) {
    __shared__ float tile[32][33];
    size_t zb = blockIdx.z;
    src += zb * (size_t)R * C;
    dst += zb * (size_t)Cpad * R;
    int c0 = blockIdx.x * 32, r0 = blockIdx.y * 32;
    int tx = threadIdx.x & 31, ty = threadIdx.x >> 5;
    #pragma unroll
    for (int i = 0; i < 4; ++i) {
        int r = r0 + ty + i * 8, c = c0 + tx;
        tile[ty + i * 8][tx] = (c < C) ? src[(size_t)r * C + c] : 0.f;
    }
    __syncthreads();
    #pragma unroll
    for (int i = 0; i < 4; ++i) {
        int c = c0 + ty + i * 8, r = r0 + tx;
        dst[(size_t)c * R + r] = __float2bfloat16(tile[tx][ty + i * 8]);
    }
}

// ---------------------------------------------------------------------------
// bf16 MFMA GEMM template. 2x2 wave grid per k-group, FMxFN fragments/wave.
// BM = 2*FM*16, BN = 2*FN*16. KG = in-block wave-split-K groups (1 or 2).
// Block = 256*KG threads. 2-buffer LDS, counted vmcnt, raw barriers.
// XCD-aware bijective block swizzle (requires nwg % 8 == 0).
// C[M,N] = A[M,K] @ Bt[N,K]^T (+bias).
// EPI 0: bias, fp32 store guarded col<Nstore (ldc=Nstore)
// EPI 1: bias+gelu, bf16 store (ldc=ldN)
// EPI 2: bias+residual add into fp32 Cf (ldc=ldN)
// ---------------------------------------------------------------------------
template <int BM, int BN, int FM, int FN, int KG, int EPI>
__global__ __launch_bounds__(256 * KG) void gemm_tile(
    const __hip_bfloat16* __restrict__ A, const __hip_bfloat16* __restrict__ Bt,
    const float* __restrict__ bias, float* __restrict__ Cf,
    __hip_bfloat16* __restrict__ Cb, int K, int ldN, int Nstore) {
    constexpr int LOADS = (BM + BN) / 32;   // gload_lds per thread per stage
    __shared__ alignas(16) __hip_bfloat16 As[KG][2][BM * 64];
    __shared__ alignas(16) __hip_bfloat16 Bs[KG][2][BN * 64];
    int tid = threadIdx.x;
    int lane = tid & 63, wave = tid >> 6;
    int g = wave >> 2;          // k-group
    int w4 = wave & 3;          // wave within group
    int wr = w4 >> 1, wc = w4 & 1;

    // XCD-aware swizzle of block -> tile mapping (nwg % 8 == 0 guaranteed)
    int gx = gridDim.x;
    int nwg = gx * gridDim.y;
    int bid = blockIdx.y * gx + blockIdx.x;
    int cpx = nwg >> 3;
    int wg = (bid & 7) * cpx + (bid >> 3);
    int row0 = (wg / gx) * BM, col0 = (wg % gx) * BN;

    int Kg = K / KG;
    int kbase = g * Kg;

    f32x4 acc[FM][FN];
    #pragma unroll
    for (int m = 0; m < FM; ++m)
        #pragma unroll
        for (int n = 0; n < FN; ++n)
            acc[m][n] = (f32x4){0.f, 0.f, 0.f, 0.f};

    int rI = lane >> 3;   // row within one staging instr (0..7)
    int cp = lane & 7;    // 16B chunk slot of a 128B row

    auto stage = [&](int buf, int k0) {
        #pragma unroll
        for (int s = 0; s < BM / 32; ++s) {
            int rbase = w4 * (BM / 4) + s * 8;
            int row = rbase + rI;
            int corig = cp ^ (row & 7);
            gload_lds16(A + (size_t)(row0 + row) * K + kbase + k0 + corig * 8,
                        (char*)As[g][buf] + rbase * 128);
        }
        #pragma unroll
        for (int s = 0; s < BN / 32; ++s) {
            int rbase = w4 * (BN / 4) + s * 8;
            int row = rbase + rI;
            int corig = cp ^ (row & 7);
            gload_lds16(Bt + (size_t)(col0 + row) * K + kbase + k0 + corig * 8,
                        (char*)Bs[g][buf] + rbase * 128);
        }
    };

    int nsteps = Kg >> 6;
    stage(0, 0);
    for (int step = 0; step < nsteps; ++step) {
        int cur = step & 1;
        __builtin_amdgcn_s_barrier();            // all waves done computing step-1
        if (step + 1 < nsteps) {
            stage(cur ^ 1, (step + 1) * 64);
            asm volatile("s_waitcnt vmcnt(%0)" :: "n"(LOADS) : "memory");
        } else {
            asm volatile("s_waitcnt vmcnt(0)" ::: "memory");
        }
        __builtin_amdgcn_sched_barrier(0);
        __builtin_amdgcn_s_barrier();            // everyone's step loads landed
        __builtin_amdgcn_sched_barrier(0);
        #pragma unroll
        for (int kk = 0; kk < 2; ++kk) {
            bf16x8 af[FM], bfr[FN];
            #pragma unroll
            for (int m = 0; m < FM; ++m) {
                int row = wr * FM * 16 + m * 16 + (lane & 15);
                int chunk = (kk * 4 + (lane >> 4)) ^ (row & 7);
                af[m] = *(const bf16x8*)((const char*)As[g][cur] + row * 128 + chunk * 16);
            }
            #pragma unroll
            for (int n = 0; n < FN; ++n) {
                int row = wc * FN * 16 + n * 16 + (lane & 15);
                int chunk = (kk * 4 + (lane >> 4)) ^ (row & 7);
                bfr[n] = *(const bf16x8*)((const char*)Bs[g][cur] + row * 128 + chunk * 16);
            }
            __builtin_amdgcn_s_setprio(1);
            #pragma unroll
            for (int m = 0; m < FM; ++m)
                #pragma unroll
                for (int n = 0; n < FN; ++n)
                    acc[m][n] = __builtin_amdgcn_mfma_f32_16x16x32_bf16(
                        af[m], bfr[n], acc[m][n], 0, 0, 0);
            __builtin_amdgcn_s_setprio(0);
        }
    }

    int cr = (lane >> 4) * 4;
    int cc = lane & 15;

    if (KG == 2) {
        // merge group 1's partial sums into group 0 via LDS (deterministic)
        float* scratch = (float*)&As[0][0][0];   // BM*BN*4 bytes needed
        __syncthreads();
        if (g == 1) {
            #pragma unroll
            for (int m = 0; m < FM; ++m)
                #pragma unroll
                for (int n = 0; n < FN; ++n)
                    #pragma unroll
                    for (int j = 0; j < 4; ++j)
                        scratch[(wr * FM * 16 + m * 16 + cr + j) * BN +
                                wc * FN * 16 + n * 16 + cc] = acc[m][n][j];
        }
        __syncthreads();
        if (g == 1) return;
        #pragma unroll
        for (int m = 0; m < FM; ++m)
            #pragma unroll
            for (int n = 0; n < FN; ++n)
                #pragma unroll
                for (int j = 0; j < 4; ++j)
                    acc[m][n][j] += scratch[(wr * FM * 16 + m * 16 + cr + j) * BN +
                                            wc * FN * 16 + n * 16 + cc];
    }

    #pragma unroll
    for (int m = 0; m < FM; ++m) {
        #pragma unroll
        for (int n = 0; n < FN; ++n) {
            #pragma unroll
            for (int j = 0; j < 4; ++j) {
                int row = row0 + wr * FM * 16 + m * 16 + cr + j;
                int col = col0 + wc * FN * 16 + n * 16 + cc;
                float v = acc[m][n][j];
                if (EPI == 0) {
                    if (col < Nstore)
                        Cf[(size_t)row * Nstore + col] = v + bias[col];
                } else if (EPI == 1) {
                    v = gelu_f(v + bias[col]);
                    Cb[(size_t)row * ldN + col] = __float2bfloat16(v);
                } else {
                    Cf[(size_t)row * ldN + col] += v + bias[col];
                }
            }
        }
    }
}

// ---------------------------------------------------------------------------
extern "C" void kernel_launch(void* const* d_in, const int* in_sizes, int n_in,
                              void* d_out, int out_size, void* d_ws, size_t ws_size,
                              hipStream_t stream) {
    const float* fg     = (const float*)d_in[0];
    const float* qf     = (const float*)d_in[1];
    const float* pos    = (const float*)d_in[2];
    const float* in_w   = (const float*)d_in[3];
    const float* in_b   = (const float*)d_in[4];
    const float* dw1_w  = (const float*)d_in[5];
    const float* dw1_b  = (const float*)d_in[6];
    const float* dw2_w  = (const float*)d_in[7];
    const float* dw2_b  = (const float*)d_in[8];
    const float* ln1_s  = (const float*)d_in[9];
    const float* ln2_s  = (const float*)d_in[10];
    const float* up_w   = (const float*)d_in[11];
    const float* up_b   = (const float*)d_in[12];
    const float* down_w = (const float*)d_in[13];
    const float* down_b = (const float*)d_in[14];
    const float* lnf_s  = (const float*)d_in[15];
    const float* out_w  = (const float*)d_in[16];
    const float* out_b  = (const float*)d_in[17];
    float* out = (float*)d_out;

    char* ws = (char*)d_ws;
    float* xa = (float*)ws;                        ws += (size_t)M_ * HID * 4;
    float* xb = (float*)ws;                        ws += (size_t)M_ * HID * 4;
    __hip_bfloat16* t1b = (__hip_bfloat16*)ws;     ws += (size_t)M_ * HID * 2;
    __hip_bfloat16* t2b = (__hip_bfloat16*)ws;     ws += (size_t)M_ * HID4 * 2;
    __hip_bfloat16* upT  = (__hip_bfloat16*)ws;    ws += (size_t)NBLK * HID4 * HID * 2;
    __hip_bfloat16* dnT  = (__hip_bfloat16*)ws;    ws += (size_t)NBLK * HID * HID4 * 2;
    __hip_bfloat16* outT = (__hip_bfloat16*)ws;    ws += (size_t)OUTP * HID * 2;

    tcvt_kernel<<<dim3(HID4 / 32, HID / 32, NBLK), 256, 0, stream>>>(
        up_w, upT, HID, HID4, HID4);
    tcvt_kernel<<<dim3(HID / 32, HID4 / 32, NBLK), 256, 0, stream>>>(
        down_w, dnT, HID4, HID, HID);
    tcvt_kernel<<<dim3(OUTP / 32, HID / 32, 1), 256, 0, stream>>>(
        out_w, outT, HID, OUT_, OUTP);

    patch_kernel<<<M_, 256, 0, stream>>>(fg, qf, pos, in_w, in_b, xa);

    float* xc = xa;
    float* xn = xb;
    for (int b = 0; b < NBLK; ++b) {
        fused_dw_kernel<<<dim3(4, N_), 512, 0, stream>>>(
            xc, xn, t1b, ln1_s + b * HID, ln2_s + b * HID,
            dw1_w + b * 3 * HID4, dw1_b + b * HID4,
            dw2_w + b * 3 * HID4, dw2_b + b * HID4);
        // up: [2048,512] @ [512,2048] -> gelu -> bf16 t2b   (256 blocks, 128^2)
        gemm_tile<128, 128, 4, 4, 1, 1><<<dim3(HID4 / 128, M_ / 128), 256, 0, stream>>>(
            t1b, upT + (size_t)b * HID4 * HID, up_b + b * HID4, nullptr, t2b,
            HID, HID4, HID4);
        // down: [2048,2048] @ [2048,512] -> += xn (fp32)    (256 blocks, split-K)
        gemm_tile<64, 64, 2, 2, 2, 2><<<dim3(HID / 64, M_ / 64), 512, 0, stream>>>(
            t2b, dnT + (size_t)b * HID * HID4, down_b + b * HID, xn, nullptr,
            HID4, HID, HID);
        float* tmp = xc; xc = xn; xn = tmp;
    }

    ln_kernel<<<M_ / 4, 256, 0, stream>>>(xc, lnf_s, t1b);
    gemm_tile<128, 64, 4, 2, 1, 0><<<dim3(OUTP / 64, M_ / 128), 256, 0, stream>>>(
        t1b, outT, out_b, out, nullptr, HID, OUT_, OUT_);
}

// Round 7
// 658.827 us; speedup vs baseline: 1.0563x; 1.0563x over previous
//
#include <hip/hip_runtime.h>
#include <hip/hip_bf16.h>

#define N_    64
#define T_    32
#define H_    64
#define W_    64
#define C_    256
#define HID   512
#define HID4  2048
#define NBLK  12
#define P_    7
#define OUT_  388
#define OUTP  448      // OUT_ padded to 64
#define CIN   51
#define M_    (N_*T_)   // 2048

typedef __attribute__((ext_vector_type(4))) float f32x4;
typedef __attribute__((ext_vector_type(8))) short bf16x8;

__device__ __forceinline__ float gelu_f(float x) {
    float x3 = x * x * x;
    return 0.5f * x * (1.f + tanhf(0.7978845608028654f * (x + 0.044715f * x3)));
}

__device__ __forceinline__ void gload_lds16(const void* g, void* l) {
    __builtin_amdgcn_global_load_lds(
        (const __attribute__((address_space(1))) void*)g,
        (__attribute__((address_space(3))) void*)l, 16, 0, 0);
}

// ---------------------------------------------------------------------------
// Patch extraction + input projection fused (unchanged)
// ---------------------------------------------------------------------------
__global__ __launch_bounds__(256) void patch_kernel(
    const float* __restrict__ fg, const float* __restrict__ qf,
    const float* __restrict__ pos, const float* __restrict__ in_w,
    const float* __restrict__ in_b, float* __restrict__ x) {
    __shared__ float4 q[64];
    __shared__ float g[8][8];
    __shared__ float xrow[CIN];
    int m = blockIdx.x;
    int n = m >> 5;
    int t = m & (T_ - 1);
    int tid = threadIdx.x, wid = tid >> 6, lane = tid & 63;
    if (tid < 64) q[tid] = *(const float4*)&qf[n * C_ + tid * 4];
    __syncthreads();
    float posy = pos[m * 2 + 0];
    float posx = pos[m * 2 + 1];
    float py = posy + 2.5f;
    float px = posx + 2.5f;
    int iy = (int)floorf(py), ix = (int)floorf(px);
    float fy = py - (float)iy, fx = px - (float)ix;
    float4 qv = q[lane];
    #pragma unroll
    for (int i = 0; i < 16; ++i) {
        int idx = wid * 16 + i;
        int a = idx >> 3, b = idx & 7;
        int y = iy + a - 6, xc = ix + b - 6;
        float partial = 0.f;
        if (y >= 0 && y < H_ && xc >= 0 && xc < W_) {
            const float4* fp = (const float4*)&fg[(((t * H_ + y) * W_) + xc) * C_];
            float4 v = fp[lane];
            partial = v.x * qv.x + v.y * qv.y + v.z * qv.z + v.w * qv.w;
        }
        #pragma unroll
        for (int o2 = 32; o2; o2 >>= 1) partial += __shfl_xor(partial, o2);
        if (lane == 0) g[a][b] = partial;
    }
    __syncthreads();
    if (tid < 49) {
        int p = tid / 7, qq = tid % 7;
        xrow[tid] = (1.f - fy) * (1.f - fx) * g[p][qq]
                  + (1.f - fy) * fx         * g[p][qq + 1]
                  + fy         * (1.f - fx) * g[p + 1][qq]
                  + fy         * fx         * g[p + 1][qq + 1];
    } else if (tid == 49) {
        xrow[49] = posy * (1.f / 64.f);
    } else if (tid == 50) {
        xrow[50] = posx * (1.f / 64.f);
    }
    __syncthreads();
    float acc0 = in_b[tid], acc1 = in_b[tid + 256];
    #pragma unroll
    for (int c = 0; c < CIN; ++c) {
        float rv = xrow[c];
        acc0 += rv * in_w[c * HID + tid];
        acc1 += rv * in_w[c * HID + tid + 256];
    }
    x[m * HID + tid] = acc0;
    x[m * HID + tid + 256] = acc1;
}

// ---------------------------------------------------------------------------
// Fully fused depthwise residual block + ln2 (unchanged)
// ---------------------------------------------------------------------------
__global__ __launch_bounds__(512) void fused_dw_kernel(
    const float* __restrict__ xin, float* __restrict__ xout,
    __hip_bfloat16* __restrict__ t1b,
    const float* __restrict__ ln1s, const float* __restrict__ ln2s,
    const float* __restrict__ w1, const float* __restrict__ b1,
    const float* __restrict__ w2, const float* __restrict__ b2) {
    __shared__ float2 part[12][8];
    int n = blockIdx.y;
    int t0 = blockIdx.x * 8;
    int j = threadIdx.x;
    int lane = j & 63, wave = j >> 6;

    float xv[12];
    #pragma unroll
    for (int tt = 0; tt < 12; ++tt) {
        int t = t0 - 2 + tt;
        xv[tt] = (t >= 0 && t < T_) ? xin[(n * T_ + t) * HID + j] : 0.f;
    }
    #pragma unroll
    for (int tt = 0; tt < 12; ++tt) {
        float s = xv[tt], q = xv[tt] * xv[tt];
        #pragma unroll
        for (int o = 32; o; o >>= 1) { s += __shfl_xor(s, o); q += __shfl_xor(q, o); }
        if (lane == 0) part[tt][wave] = make_float2(s, q);
    }
    __syncthreads();
    float s1v = ln1s[j];
    float xl[12];
    #pragma unroll
    for (int tt = 0; tt < 12; ++tt) {
        int t = t0 - 2 + tt;
        if (t >= 0 && t < T_) {
            float s = 0.f, q = 0.f;
            #pragma unroll
            for (int w = 0; w < 8; ++w) { float2 p = part[tt][w]; s += p.x; q += p.y; }
            float mean = s * (1.f / HID);
            float var  = q * (1.f / HID) - mean * mean;
            xl[tt] = (xv[tt] - mean) * rsqrtf(var + 1e-5f) * s1v;
        } else xl[tt] = 0.f;
    }
    float w1a[12], w2a[12], b1a[4];
    #pragma unroll
    for (int r = 0; r < 3; ++r) {
        *(float4*)&w1a[r * 4] = *(const float4*)&w1[r * HID4 + 4 * j];
        *(float4*)&w2a[r * 4] = *(const float4*)&w2[r * HID4 + 4 * j];
    }
    *(float4*)&b1a[0] = *(const float4*)&b1[4 * j];
    float4 b2v = *(const float4*)&b2[4 * j];
    float h[8];
    float b2sum = b2v.x + b2v.y + b2v.z + b2v.w;
    #pragma unroll
    for (int i = 0; i < 8; ++i) h[i] = b2sum;
    #pragma unroll
    for (int k = 0; k < 4; ++k) {
        float gk[10];
        #pragma unroll
        for (int idx = 0; idx < 10; ++idx) {
            int tp = t0 - 1 + idx;
            if (tp >= 0 && tp < T_) {
                float a = b1a[k] + w1a[0 * 4 + k] * xl[idx]
                                 + w1a[1 * 4 + k] * xl[idx + 1]
                                 + w1a[2 * 4 + k] * xl[idx + 2];
                gk[idx] = gelu_f(a);
            } else gk[idx] = 0.f;
        }
        #pragma unroll
        for (int i = 0; i < 8; ++i)
            h[i] += w2a[0 * 4 + k] * gk[i] + w2a[1 * 4 + k] * gk[i + 1]
                  + w2a[2 * 4 + k] * gk[i + 2];
    }
    float xn[8];
    #pragma unroll
    for (int i = 0; i < 8; ++i) xn[i] = xv[i + 2] + h[i];
    __syncthreads();
    #pragma unroll
    for (int i = 0; i < 8; ++i) {
        float s = xn[i], q = xn[i] * xn[i];
        #pragma unroll
        for (int o = 32; o; o >>= 1) { s += __shfl_xor(s, o); q += __shfl_xor(q, o); }
        if (lane == 0) part[i][wave] = make_float2(s, q);
    }
    __syncthreads();
    float s2v = ln2s[j];
    #pragma unroll
    for (int i = 0; i < 8; ++i) {
        float s = 0.f, q = 0.f;
        #pragma unroll
        for (int w = 0; w < 8; ++w) { float2 p = part[i][w]; s += p.x; q += p.y; }
        float mean = s * (1.f / HID);
        float var  = q * (1.f / HID) - mean * mean;
        float rstd = rsqrtf(var + 1e-5f);
        int m = (n * T_ + t0 + i) * HID + j;
        xout[m] = xn[i];
        t1b[m] = __float2bfloat16((xn[i] - mean) * rstd * s2v);
    }
}

// ---------------------------------------------------------------------------
// LayerNorm bf16-out (final LN only, unchanged)
// ---------------------------------------------------------------------------
__global__ __launch_bounds__(256) void ln_kernel(
    const float* __restrict__ in, const float* __restrict__ s,
    __hip_bfloat16* __restrict__ outb) {
    int wid = threadIdx.x >> 6, lane = threadIdx.x & 63;
    int row = blockIdx.x * 4 + wid;
    const float* r = in + row * HID + lane * 8;
    float4 v0 = *(const float4*)r;
    float4 v1 = *(const float4*)(r + 4);
    float sum = v0.x + v0.y + v0.z + v0.w + v1.x + v1.y + v1.z + v1.w;
    float sq  = v0.x*v0.x + v0.y*v0.y + v0.z*v0.z + v0.w*v0.w
              + v1.x*v1.x + v1.y*v1.y + v1.z*v1.z + v1.w*v1.w;
    #pragma unroll
    for (int o = 32; o; o >>= 1) { sum += __shfl_xor(sum, o); sq += __shfl_xor(sq, o); }
    float mean = sum * (1.f / HID);
    float var  = sq * (1.f / HID) - mean * mean;
    float rstd = rsqrtf(var + 1e-5f);
    const float* sp = s + lane * 8;
    float4 s0 = *(const float4*)sp;
    float4 s1 = *(const float4*)(sp + 4);
    float o[8];
    o[0] = (v0.x - mean) * rstd * s0.x; o[1] = (v0.y - mean) * rstd * s0.y;
    o[2] = (v0.z - mean) * rstd * s0.z; o[3] = (v0.w - mean) * rstd * s0.w;
    o[4] = (v1.x - mean) * rstd * s1.x; o[5] = (v1.y - mean) * rstd * s1.y;
    o[6] = (v1.z - mean) * rstd * s1.z; o[7] = (v1.w - mean) * rstd * s1.w;
    alignas(16) __hip_bfloat16 tmp[8];
    #pragma unroll
    for (int i = 0; i < 8; ++i) tmp[i] = __float2bfloat16(o[i]);
    *(bf16x8*)&outb[row * HID + lane * 8] = *(bf16x8*)tmp;
}

// ---------------------------------------------------------------------------
// Transpose + fp32 -> bf16 convert (weights, unchanged)
// ---------------------------------------------------------------------------
__global__ __launch_bounds__(256) void tcvt_kernel(
    const float* __restrict__ src, __hip_bfloat16* __restrict__ dst,
    int R, int C, int Cpad) {
    __shared__ float tile[32][33];
    size_t zb = blockIdx.z;
    src += zb * (size_t)R * C;
    dst += zb * (size_t)Cpad * R;
    int c0 = blockIdx.x * 32, r0 = blockIdx.y * 32;
    int tx = threadIdx.x & 31, ty = threadIdx.x >> 5;
    #pragma unroll
    for (int i = 0; i < 4; ++i) {
        int r = r0 + ty + i * 8, c = c0 + tx;
        tile[ty + i * 8][tx] = (c < C) ? src[(size_t)r * C + c] : 0.f;
    }
    __syncthreads();
    #pragma unroll
    for (int i = 0; i < 4; ++i) {
        int c = c0 + ty + i * 8, r = r0 + tx;
        dst[(size_t)c * R + r] = __float2bfloat16(tile[tx][ty + i * 8]);
    }
}

// ---------------------------------------------------------------------------
// bf16 MFMA GEMM template. Per k-group: 2x2 waves, wave tile (FM*16)x(FN*16).
// BM = 2*FM*16, BN = 2*FN*16. KG = in-block wave-split-K groups (1 or 2).
// Block = 256*KG threads. 2-buffer LDS, counted vmcnt, raw barriers.
// C[M,N] = A[M,K] @ Bt[N,K]^T (+bias).
// EPI 0: bias, fp32 store guarded col<Nstore (ldc=Nstore)
// EPI 1: bias+gelu, bf16 store (ldc=ldN)
// EPI 2: bias+residual add into fp32 Cf (ldc=ldN)
// ---------------------------------------------------------------------------
template <int BM, int BN, int FM, int FN, int KG, int EPI>
__global__ __launch_bounds__(256 * KG) void gemm_tile(
    const __hip_bfloat16* __restrict__ A, const __hip_bfloat16* __restrict__ Bt,
    const float* __restrict__ bias, float* __restrict__ Cf,
    __hip_bfloat16* __restrict__ Cb, int K, int ldN, int Nstore) {
    constexpr int LOADS = (BM + BN) / 32;   // gload_lds per thread per stage
    __shared__ alignas(16) __hip_bfloat16 As[KG][2][BM * 64];
    __shared__ alignas(16) __hip_bfloat16 Bs[KG][2][BN * 64];
    int tid = threadIdx.x;
    int lane = tid & 63, wave = tid >> 6;
    int g = wave >> 2;          // k-group
    int w4 = wave & 3;          // wave within group
    int wr = w4 >> 1, wc = w4 & 1;
    int row0 = blockIdx.y * BM, col0 = blockIdx.x * BN;

    int Kg = K / KG;
    int kbase = g * Kg;

    f32x4 acc[FM][FN];
    #pragma unroll
    for (int m = 0; m < FM; ++m)
        #pragma unroll
        for (int n = 0; n < FN; ++n)
            acc[m][n] = (f32x4){0.f, 0.f, 0.f, 0.f};

    int rI = lane >> 3;   // row within one staging instr (0..7)
    int cp = lane & 7;    // 16B chunk slot of a 128B row

    auto stage = [&](int buf, int k0) {
        #pragma unroll
        for (int s = 0; s < BM / 32; ++s) {
            int rbase = w4 * (BM / 4) + s * 8;
            int row = rbase + rI;
            int corig = cp ^ (row & 7);
            gload_lds16(A + (size_t)(row0 + row) * K + kbase + k0 + corig * 8,
                        (char*)As[g][buf] + rbase * 128);
        }
        #pragma unroll
        for (int s = 0; s < BN / 32; ++s) {
            int rbase = w4 * (BN / 4) + s * 8;
            int row = rbase + rI;
            int corig = cp ^ (row & 7);
            gload_lds16(Bt + (size_t)(col0 + row) * K + kbase + k0 + corig * 8,
                        (char*)Bs[g][buf] + rbase * 128);
        }
    };

    int nsteps = Kg >> 6;
    stage(0, 0);
    for (int step = 0; step < nsteps; ++step) {
        int cur = step & 1;
        __builtin_amdgcn_s_barrier();            // all waves done computing step-1
        if (step + 1 < nsteps) {
            stage(cur ^ 1, (step + 1) * 64);
            asm volatile("s_waitcnt vmcnt(%0)" :: "n"(LOADS) : "memory");
        } else {
            asm volatile("s_waitcnt vmcnt(0)" ::: "memory");
        }
        __builtin_amdgcn_sched_barrier(0);
        __builtin_amdgcn_s_barrier();            // everyone's step loads landed
        __builtin_amdgcn_sched_barrier(0);
        #pragma unroll
        for (int kk = 0; kk < 2; ++kk) {
            bf16x8 af[FM], bfr[FN];
            #pragma unroll
            for (int m = 0; m < FM; ++m) {
                int row = wr * FM * 16 + m * 16 + (lane & 15);
                int chunk = (kk * 4 + (lane >> 4)) ^ (row & 7);
                af[m] = *(const bf16x8*)((const char*)As[g][cur] + row * 128 + chunk * 16);
            }
            #pragma unroll
            for (int n = 0; n < FN; ++n) {
                int row = wc * FN * 16 + n * 16 + (lane & 15);
                int chunk = (kk * 4 + (lane >> 4)) ^ (row & 7);
                bfr[n] = *(const bf16x8*)((const char*)Bs[g][cur] + row * 128 + chunk * 16);
            }
            __builtin_amdgcn_s_setprio(1);
            #pragma unroll
            for (int m = 0; m < FM; ++m)
                #pragma unroll
                for (int n = 0; n < FN; ++n)
                    acc[m][n] = __builtin_amdgcn_mfma_f32_16x16x32_bf16(
                        af[m], bfr[n], acc[m][n], 0, 0, 0);
            __builtin_amdgcn_s_setprio(0);
        }
    }

    int cr = (lane >> 4) * 4;
    int cc = lane & 15;

    if (KG == 2) {
        // merge group 1's partial sums into group 0 via LDS (deterministic)
        float* scratch = (float*)&As[0][0][0];   // BM*BN*4 bytes needed
        __syncthreads();
        if (g == 1) {
            #pragma unroll
            for (int m = 0; m < FM; ++m)
                #pragma unroll
                for (int n = 0; n < FN; ++n)
                    #pragma unroll
                    for (int j = 0; j < 4; ++j)
                        scratch[(wr * FM * 16 + m * 16 + cr + j) * BN +
                                wc * FN * 16 + n * 16 + cc] = acc[m][n][j];
        }
        __syncthreads();
        if (g == 1) return;
        #pragma unroll
        for (int m = 0; m < FM; ++m)
            #pragma unroll
            for (int n = 0; n < FN; ++n)
                #pragma unroll
                for (int j = 0; j < 4; ++j)
                    acc[m][n][j] += scratch[(wr * FM * 16 + m * 16 + cr + j) * BN +
                                            wc * FN * 16 + n * 16 + cc];
    }

    #pragma unroll
    for (int m = 0; m < FM; ++m) {
        #pragma unroll
        for (int n = 0; n < FN; ++n) {
            #pragma unroll
            for (int j = 0; j < 4; ++j) {
                int row = row0 + wr * FM * 16 + m * 16 + cr + j;
                int col = col0 + wc * FN * 16 + n * 16 + cc;
                float v = acc[m][n][j];
                if (EPI == 0) {
                    if (col < Nstore)
                        Cf[(size_t)row * Nstore + col] = v + bias[col];
                } else if (EPI == 1) {
                    v = gelu_f(v + bias[col]);
                    Cb[(size_t)row * ldN + col] = __float2bfloat16(v);
                } else {
                    Cf[(size_t)row * ldN + col] += v + bias[col];
                }
            }
        }
    }
}

// ---------------------------------------------------------------------------
extern "C" void kernel_launch(void* const* d_in, const int* in_sizes, int n_in,
                              void* d_out, int out_size, void* d_ws, size_t ws_size,
                              hipStream_t stream) {
    const float* fg     = (const float*)d_in[0];
    const float* qf     = (const float*)d_in[1];
    const float* pos    = (const float*)d_in[2];
    const float* in_w   = (const float*)d_in[3];
    const float* in_b   = (const float*)d_in[4];
    const float* dw1_w  = (const float*)d_in[5];
    const float* dw1_b  = (const float*)d_in[6];
    const float* dw2_w  = (const float*)d_in[7];
    const float* dw2_b  = (const float*)d_in[8];
    const float* ln1_s  = (const float*)d_in[9];
    const float* ln2_s  = (const float*)d_in[10];
    const float* up_w   = (const float*)d_in[11];
    const float* up_b   = (const float*)d_in[12];
    const float* down_w = (const float*)d_in[13];
    const float* down_b = (const float*)d_in[14];
    const float* lnf_s  = (const float*)d_in[15];
    const float* out_w  = (const float*)d_in[16];
    const float* out_b  = (const float*)d_in[17];
    float* out = (float*)d_out;

    char* ws = (char*)d_ws;
    float* xa = (float*)ws;                        ws += (size_t)M_ * HID * 4;
    float* xb = (float*)ws;                        ws += (size_t)M_ * HID * 4;
    __hip_bfloat16* t1b = (__hip_bfloat16*)ws;     ws += (size_t)M_ * HID * 2;
    __hip_bfloat16* t2b = (__hip_bfloat16*)ws;     ws += (size_t)M_ * HID4 * 2;
    __hip_bfloat16* upT  = (__hip_bfloat16*)ws;    ws += (size_t)NBLK * HID4 * HID * 2;
    __hip_bfloat16* dnT  = (__hip_bfloat16*)ws;    ws += (size_t)NBLK * HID * HID4 * 2;
    __hip_bfloat16* outT = (__hip_bfloat16*)ws;    ws += (size_t)OUTP * HID * 2;

    tcvt_kernel<<<dim3(HID4 / 32, HID / 32, NBLK), 256, 0, stream>>>(
        up_w, upT, HID, HID4, HID4);
    tcvt_kernel<<<dim3(HID / 32, HID4 / 32, NBLK), 256, 0, stream>>>(
        down_w, dnT, HID4, HID, HID);
    tcvt_kernel<<<dim3(OUTP / 32, HID / 32, 1), 256, 0, stream>>>(
        out_w, outT, HID, OUT_, OUTP);

    patch_kernel<<<M_, 256, 0, stream>>>(fg, qf, pos, in_w, in_b, xa);

    float* xc = xa;
    float* xn = xb;
    for (int b = 0; b < NBLK; ++b) {
        fused_dw_kernel<<<dim3(4, N_), 512, 0, stream>>>(
            xc, xn, t1b, ln1_s + b * HID, ln2_s + b * HID,
            dw1_w + b * 3 * HID4, dw1_b + b * HID4,
            dw2_w + b * 3 * HID4, dw2_b + b * HID4);
        // up: [2048,512] @ [512,2048] -> gelu -> bf16 t2b
        // 128x64 tile, 4x2 frags, 512 blocks (~2-3 resident/CU)
        gemm_tile<128, 64, 4, 2, 1, 1><<<dim3(HID4 / 64, M_ / 128), 256, 0, stream>>>(
            t1b, upT + (size_t)b * HID4 * HID, up_b + b * HID4, nullptr, t2b,
            HID, HID4, HID4);
        // down: [2048,2048] @ [2048,512] -> += xn (fp32)  (256 blocks, split-K)
        gemm_tile<64, 64, 2, 2, 2, 2><<<dim3(HID / 64, M_ / 64), 512, 0, stream>>>(
            t2b, dnT + (size_t)b * HID * HID4, down_b + b * HID, xn, nullptr,
            HID4, HID, HID);
        float* tmp = xc; xc = xn; xn = tmp;
    }

    ln_kernel<<<M_ / 4, 256, 0, stream>>>(xc, lnf_s, t1b);
    gemm_tile<128, 64, 4, 2, 1, 0><<<dim3(OUTP / 64, M_ / 128), 256, 0, stream>>>(
        t1b, outT, out_b, out, nullptr, HID, OUT_, OUT_);
}

// Round 8
// 612.961 us; speedup vs baseline: 1.1354x; 1.0748x over previous
//
#include <hip/hip_runtime.h>
#include <hip/hip_bf16.h>

#define N_    64
#define T_    32
#define H_    64
#define W_    64
#define C_    256
#define HID   512
#define HID4  2048
#define NBLK  12
#define P_    7
#define OUT_  388
#define OUTP  448      // OUT_ padded to 64
#define CIN   51
#define M_    (N_*T_)   // 2048

typedef __attribute__((ext_vector_type(4))) float f32x4;
typedef __attribute__((ext_vector_type(8))) short bf16x8;

__device__ __forceinline__ float gelu_f(float x) {
    float x3 = x * x * x;
    return 0.5f * x * (1.f + tanhf(0.7978845608028654f * (x + 0.044715f * x3)));
}

__device__ __forceinline__ void gload_lds16(const void* g, void* l) {
    __builtin_amdgcn_global_load_lds(
        (const __attribute__((address_space(1))) void*)g,
        (__attribute__((address_space(3))) void*)l, 16, 0, 0);
}

// ---------------------------------------------------------------------------
// Patch extraction + input projection fused (unchanged)
// ---------------------------------------------------------------------------
__global__ __launch_bounds__(256) void patch_kernel(
    const float* __restrict__ fg, const float* __restrict__ qf,
    const float* __restrict__ pos, const float* __restrict__ in_w,
    const float* __restrict__ in_b, float* __restrict__ x) {
    __shared__ float4 q[64];
    __shared__ float g[8][8];
    __shared__ float xrow[CIN];
    int m = blockIdx.x;
    int n = m >> 5;
    int t = m & (T_ - 1);
    int tid = threadIdx.x, wid = tid >> 6, lane = tid & 63;
    if (tid < 64) q[tid] = *(const float4*)&qf[n * C_ + tid * 4];
    __syncthreads();
    float posy = pos[m * 2 + 0];
    float posx = pos[m * 2 + 1];
    float py = posy + 2.5f;
    float px = posx + 2.5f;
    int iy = (int)floorf(py), ix = (int)floorf(px);
    float fy = py - (float)iy, fx = px - (float)ix;
    float4 qv = q[lane];
    #pragma unroll
    for (int i = 0; i < 16; ++i) {
        int idx = wid * 16 + i;
        int a = idx >> 3, b = idx & 7;
        int y = iy + a - 6, xc = ix + b - 6;
        float partial = 0.f;
        if (y >= 0 && y < H_ && xc >= 0 && xc < W_) {
            const float4* fp = (const float4*)&fg[(((t * H_ + y) * W_) + xc) * C_];
            float4 v = fp[lane];
            partial = v.x * qv.x + v.y * qv.y + v.z * qv.z + v.w * qv.w;
        }
        #pragma unroll
        for (int o2 = 32; o2; o2 >>= 1) partial += __shfl_xor(partial, o2);
        if (lane == 0) g[a][b] = partial;
    }
    __syncthreads();
    if (tid < 49) {
        int p = tid / 7, qq = tid % 7;
        xrow[tid] = (1.f - fy) * (1.f - fx) * g[p][qq]
                  + (1.f - fy) * fx         * g[p][qq + 1]
                  + fy         * (1.f - fx) * g[p + 1][qq]
                  + fy         * fx         * g[p + 1][qq + 1];
    } else if (tid == 49) {
        xrow[49] = posy * (1.f / 64.f);
    } else if (tid == 50) {
        xrow[50] = posx * (1.f / 64.f);
    }
    __syncthreads();
    float acc0 = in_b[tid], acc1 = in_b[tid + 256];
    #pragma unroll
    for (int c = 0; c < CIN; ++c) {
        float rv = xrow[c];
        acc0 += rv * in_w[c * HID + tid];
        acc1 += rv * in_w[c * HID + tid + 256];
    }
    x[m * HID + tid] = acc0;
    x[m * HID + tid + 256] = acc1;
}

// ---------------------------------------------------------------------------
// Fully fused depthwise residual block + ln2 (unchanged)
// ---------------------------------------------------------------------------
__global__ __launch_bounds__(512) void fused_dw_kernel(
    const float* __restrict__ xin, float* __restrict__ xout,
    __hip_bfloat16* __restrict__ t1b,
    const float* __restrict__ ln1s, const float* __restrict__ ln2s,
    const float* __restrict__ w1, const float* __restrict__ b1,
    const float* __restrict__ w2, const float* __restrict__ b2) {
    __shared__ float2 part[12][8];
    int n = blockIdx.y;
    int t0 = blockIdx.x * 8;
    int j = threadIdx.x;
    int lane = j & 63, wave = j >> 6;

    float xv[12];
    #pragma unroll
    for (int tt = 0; tt < 12; ++tt) {
        int t = t0 - 2 + tt;
        xv[tt] = (t >= 0 && t < T_) ? xin[(n * T_ + t) * HID + j] : 0.f;
    }
    #pragma unroll
    for (int tt = 0; tt < 12; ++tt) {
        float s = xv[tt], q = xv[tt] * xv[tt];
        #pragma unroll
        for (int o = 32; o; o >>= 1) { s += __shfl_xor(s, o); q += __shfl_xor(q, o); }
        if (lane == 0) part[tt][wave] = make_float2(s, q);
    }
    __syncthreads();
    float s1v = ln1s[j];
    float xl[12];
    #pragma unroll
    for (int tt = 0; tt < 12; ++tt) {
        int t = t0 - 2 + tt;
        if (t >= 0 && t < T_) {
            float s = 0.f, q = 0.f;
            #pragma unroll
            for (int w = 0; w < 8; ++w) { float2 p = part[tt][w]; s += p.x; q += p.y; }
            float mean = s * (1.f / HID);
            float var  = q * (1.f / HID) - mean * mean;
            xl[tt] = (xv[tt] - mean) * rsqrtf(var + 1e-5f) * s1v;
        } else xl[tt] = 0.f;
    }
    float w1a[12], w2a[12], b1a[4];
    #pragma unroll
    for (int r = 0; r < 3; ++r) {
        *(float4*)&w1a[r * 4] = *(const float4*)&w1[r * HID4 + 4 * j];
        *(float4*)&w2a[r * 4] = *(const float4*)&w2[r * HID4 + 4 * j];
    }
    *(float4*)&b1a[0] = *(const float4*)&b1[4 * j];
    float4 b2v = *(const float4*)&b2[4 * j];
    float h[8];
    float b2sum = b2v.x + b2v.y + b2v.z + b2v.w;
    #pragma unroll
    for (int i = 0; i < 8; ++i) h[i] = b2sum;
    #pragma unroll
    for (int k = 0; k < 4; ++k) {
        float gk[10];
        #pragma unroll
        for (int idx = 0; idx < 10; ++idx) {
            int tp = t0 - 1 + idx;
            if (tp >= 0 && tp < T_) {
                float a = b1a[k] + w1a[0 * 4 + k] * xl[idx]
                                 + w1a[1 * 4 + k] * xl[idx + 1]
                                 + w1a[2 * 4 + k] * xl[idx + 2];
                gk[idx] = gelu_f(a);
            } else gk[idx] = 0.f;
        }
        #pragma unroll
        for (int i = 0; i < 8; ++i)
            h[i] += w2a[0 * 4 + k] * gk[i] + w2a[1 * 4 + k] * gk[i + 1]
                  + w2a[2 * 4 + k] * gk[i + 2];
    }
    float xn[8];
    #pragma unroll
    for (int i = 0; i < 8; ++i) xn[i] = xv[i + 2] + h[i];
    __syncthreads();
    #pragma unroll
    for (int i = 0; i < 8; ++i) {
        float s = xn[i], q = xn[i] * xn[i];
        #pragma unroll
        for (int o = 32; o; o >>= 1) { s += __shfl_xor(s, o); q += __shfl_xor(q, o); }
        if (lane == 0) part[i][wave] = make_float2(s, q);
    }
    __syncthreads();
    float s2v = ln2s[j];
    #pragma unroll
    for (int i = 0; i < 8; ++i) {
        float s = 0.f, q = 0.f;
        #pragma unroll
        for (int w = 0; w < 8; ++w) { float2 p = part[i][w]; s += p.x; q += p.y; }
        float mean = s * (1.f / HID);
        float var  = q * (1.f / HID) - mean * mean;
        float rstd = rsqrtf(var + 1e-5f);
        int m = (n * T_ + t0 + i) * HID + j;
        xout[m] = xn[i];
        t1b[m] = __float2bfloat16((xn[i] - mean) * rstd * s2v);
    }
}

// ---------------------------------------------------------------------------
// LayerNorm bf16-out (final LN only, unchanged)
// ---------------------------------------------------------------------------
__global__ __launch_bounds__(256) void ln_kernel(
    const float* __restrict__ in, const float* __restrict__ s,
    __hip_bfloat16* __restrict__ outb) {
    int wid = threadIdx.x >> 6, lane = threadIdx.x & 63;
    int row = blockIdx.x * 4 + wid;
    const float* r = in + row * HID + lane * 8;
    float4 v0 = *(const float4*)r;
    float4 v1 = *(const float4*)(r + 4);
    float sum = v0.x + v0.y + v0.z + v0.w + v1.x + v1.y + v1.z + v1.w;
    float sq  = v0.x*v0.x + v0.y*v0.y + v0.z*v0.z + v0.w*v0.w
              + v1.x*v1.x + v1.y*v1.y + v1.z*v1.z + v1.w*v1.w;
    #pragma unroll
    for (int o = 32; o; o >>= 1) { sum += __shfl_xor(sum, o); sq += __shfl_xor(sq, o); }
    float mean = sum * (1.f / HID);
    float var  = sq * (1.f / HID) - mean * mean;
    float rstd = rsqrtf(var + 1e-5f);
    const float* sp = s + lane * 8;
    float4 s0 = *(const float4*)sp;
    float4 s1 = *(const float4*)(sp + 4);
    float o[8];
    o[0] = (v0.x - mean) * rstd * s0.x; o[1] = (v0.y - mean) * rstd * s0.y;
    o[2] = (v0.z - mean) * rstd * s0.z; o[3] = (v0.w - mean) * rstd * s0.w;
    o[4] = (v1.x - mean) * rstd * s1.x; o[5] = (v1.y - mean) * rstd * s1.y;
    o[6] = (v1.z - mean) * rstd * s1.z; o[7] = (v1.w - mean) * rstd * s1.w;
    alignas(16) __hip_bfloat16 tmp[8];
    #pragma unroll
    for (int i = 0; i < 8; ++i) tmp[i] = __float2bfloat16(o[i]);
    *(bf16x8*)&outb[row * HID + lane * 8] = *(bf16x8*)tmp;
}

// ---------------------------------------------------------------------------
// Transpose + fp32 -> bf16 convert (weights, unchanged)
// ---------------------------------------------------------------------------
__global__ __launch_bounds__(256) void tcvt_kernel(
    const float* __restrict__ src, __hip_bfloat16* __restrict__ dst,
    int R, int C, int Cpad) {
    __shared__ float tile[32][33];
    size_t zb = blockIdx.z;
    src += zb * (size_t)R * C;
    dst += zb * (size_t)Cpad * R;
    int c0 = blockIdx.x * 32, r0 = blockIdx.y * 32;
    int tx = threadIdx.x & 31, ty = threadIdx.x >> 5;
    #pragma unroll
    for (int i = 0; i < 4; ++i) {
        int r = r0 + ty + i * 8, c = c0 + tx;
        tile[ty + i * 8][tx] = (c < C) ? src[(size_t)r * C + c] : 0.f;
    }
    __syncthreads();
    #pragma unroll
    for (int i = 0; i < 4; ++i) {
        int c = c0 + ty + i * 8, r = r0 + tx;
        dst[(size_t)c * R + r] = __float2bfloat16(tile[tx][ty + i * 8]);
    }
}

// ---------------------------------------------------------------------------
// bf16 MFMA GEMM template. Per k-group: 2x2 waves, wave tile (FM*16)x(FN*16).
// BM = 2*FM*16, BN = 2*FN*16. KG = in-block wave-split-K groups (1 or 2).
// Block = 256*KG threads. 2-buffer LDS, counted vmcnt, raw barriers.
// SWZ = 1: XCD-ownership swizzle — XCD (bid&7) owns a contiguous chunk of
// Mtiles/8 M-tiles across all N, so A-panels are fetched once per XCD and
// consecutive blocks within an XCD share the B-panel. Requires Mtiles%8==0.
// C[M,N] = A[M,K] @ Bt[N,K]^T (+bias).
// EPI 0: bias, fp32 store guarded col<Nstore (ldc=Nstore)
// EPI 1: bias+gelu, bf16 store (ldc=ldN)
// EPI 2: bias+residual add into fp32 Cf (ldc=ldN)
// ---------------------------------------------------------------------------
template <int BM, int BN, int FM, int FN, int KG, int EPI, int SWZ>
__global__ __launch_bounds__(256 * KG) void gemm_tile(
    const __hip_bfloat16* __restrict__ A, const __hip_bfloat16* __restrict__ Bt,
    const float* __restrict__ bias, float* __restrict__ Cf,
    __hip_bfloat16* __restrict__ Cb, int K, int ldN, int Nstore) {
    constexpr int LOADS = (BM + BN) / 32;   // gload_lds per thread per stage
    __shared__ alignas(16) __hip_bfloat16 As[KG][2][BM * 64];
    __shared__ alignas(16) __hip_bfloat16 Bs[KG][2][BN * 64];
    int tid = threadIdx.x;
    int lane = tid & 63, wave = tid >> 6;
    int g = wave >> 2;          // k-group
    int w4 = wave & 3;          // wave within group
    int wr = w4 >> 1, wc = w4 & 1;

    int row0, col0;
    if (SWZ) {
        int bid = blockIdx.y * gridDim.x + blockIdx.x;
        int chunk = gridDim.y >> 3;          // M-tiles per XCD
        int xcd = bid & 7;
        int i = bid >> 3;
        int mt = xcd * chunk + (i % chunk);
        int nt = i / chunk;
        row0 = mt * BM; col0 = nt * BN;
    } else {
        row0 = blockIdx.y * BM; col0 = blockIdx.x * BN;
    }

    int Kg = K / KG;
    int kbase = g * Kg;

    f32x4 acc[FM][FN];
    #pragma unroll
    for (int m = 0; m < FM; ++m)
        #pragma unroll
        for (int n = 0; n < FN; ++n)
            acc[m][n] = (f32x4){0.f, 0.f, 0.f, 0.f};

    int rI = lane >> 3;   // row within one staging instr (0..7)
    int cp = lane & 7;    // 16B chunk slot of a 128B row

    auto stage = [&](int buf, int k0) {
        #pragma unroll
        for (int s = 0; s < BM / 32; ++s) {
            int rbase = w4 * (BM / 4) + s * 8;
            int row = rbase + rI;
            int corig = cp ^ (row & 7);
            gload_lds16(A + (size_t)(row0 + row) * K + kbase + k0 + corig * 8,
                        (char*)As[g][buf] + rbase * 128);
        }
        #pragma unroll
        for (int s = 0; s < BN / 32; ++s) {
            int rbase = w4 * (BN / 4) + s * 8;
            int row = rbase + rI;
            int corig = cp ^ (row & 7);
            gload_lds16(Bt + (size_t)(col0 + row) * K + kbase + k0 + corig * 8,
                        (char*)Bs[g][buf] + rbase * 128);
        }
    };

    int nsteps = Kg >> 6;
    stage(0, 0);
    for (int step = 0; step < nsteps; ++step) {
        int cur = step & 1;
        __builtin_amdgcn_s_barrier();            // all waves done computing step-1
        if (step + 1 < nsteps) {
            stage(cur ^ 1, (step + 1) * 64);
            asm volatile("s_waitcnt vmcnt(%0)" :: "n"(LOADS) : "memory");
        } else {
            asm volatile("s_waitcnt vmcnt(0)" ::: "memory");
        }
        __builtin_amdgcn_sched_barrier(0);
        __builtin_amdgcn_s_barrier();            // everyone's step loads landed
        __builtin_amdgcn_sched_barrier(0);
        #pragma unroll
        for (int kk = 0; kk < 2; ++kk) {
            bf16x8 af[FM], bfr[FN];
            #pragma unroll
            for (int m = 0; m < FM; ++m) {
                int row = wr * FM * 16 + m * 16 + (lane & 15);
                int chunk = (kk * 4 + (lane >> 4)) ^ (row & 7);
                af[m] = *(const bf16x8*)((const char*)As[g][cur] + row * 128 + chunk * 16);
            }
            #pragma unroll
            for (int n = 0; n < FN; ++n) {
                int row = wc * FN * 16 + n * 16 + (lane & 15);
                int chunk = (kk * 4 + (lane >> 4)) ^ (row & 7);
                bfr[n] = *(const bf16x8*)((const char*)Bs[g][cur] + row * 128 + chunk * 16);
            }
            __builtin_amdgcn_s_setprio(1);
            #pragma unroll
            for (int m = 0; m < FM; ++m)
                #pragma unroll
                for (int n = 0; n < FN; ++n)
                    acc[m][n] = __builtin_amdgcn_mfma_f32_16x16x32_bf16(
                        af[m], bfr[n], acc[m][n], 0, 0, 0);
            __builtin_amdgcn_s_setprio(0);
        }
    }

    int cr = (lane >> 4) * 4;
    int cc = lane & 15;

    if (KG == 2) {
        // merge group 1's partial sums into group 0 via LDS (deterministic)
        float* scratch = (float*)&As[0][0][0];   // BM*BN*4 bytes needed
        __syncthreads();
        if (g == 1) {
            #pragma unroll
            for (int m = 0; m < FM; ++m)
                #pragma unroll
                for (int n = 0; n < FN; ++n)
                    #pragma unroll
                    for (int j = 0; j < 4; ++j)
                        scratch[(wr * FM * 16 + m * 16 + cr + j) * BN +
                                wc * FN * 16 + n * 16 + cc] = acc[m][n][j];
        }
        __syncthreads();
        if (g == 1) return;
        #pragma unroll
        for (int m = 0; m < FM; ++m)
            #pragma unroll
            for (int n = 0; n < FN; ++n)
                #pragma unroll
                for (int j = 0; j < 4; ++j)
                    acc[m][n][j] += scratch[(wr * FM * 16 + m * 16 + cr + j) * BN +
                                            wc * FN * 16 + n * 16 + cc];
    }

    #pragma unroll
    for (int m = 0; m < FM; ++m) {
        #pragma unroll
        for (int n = 0; n < FN; ++n) {
            #pragma unroll
            for (int j = 0; j < 4; ++j) {
                int row = row0 + wr * FM * 16 + m * 16 + cr + j;
                int col = col0 + wc * FN * 16 + n * 16 + cc;
                float v = acc[m][n][j];
                if (EPI == 0) {
                    if (col < Nstore)
                        Cf[(size_t)row * Nstore + col] = v + bias[col];
                } else if (EPI == 1) {
                    v = gelu_f(v + bias[col]);
                    Cb[(size_t)row * ldN + col] = __float2bfloat16(v);
                } else {
                    Cf[(size_t)row * ldN + col] += v + bias[col];
                }
            }
        }
    }
}

// ---------------------------------------------------------------------------
extern "C" void kernel_launch(void* const* d_in, const int* in_sizes, int n_in,
                              void* d_out, int out_size, void* d_ws, size_t ws_size,
                              hipStream_t stream) {
    const float* fg     = (const float*)d_in[0];
    const float* qf     = (const float*)d_in[1];
    const float* pos    = (const float*)d_in[2];
    const float* in_w   = (const float*)d_in[3];
    const float* in_b   = (const float*)d_in[4];
    const float* dw1_w  = (const float*)d_in[5];
    const float* dw1_b  = (const float*)d_in[6];
    const float* dw2_w  = (const float*)d_in[7];
    const float* dw2_b  = (const float*)d_in[8];
    const float* ln1_s  = (const float*)d_in[9];
    const float* ln2_s  = (const float*)d_in[10];
    const float* up_w   = (const float*)d_in[11];
    const float* up_b   = (const float*)d_in[12];
    const float* down_w = (const float*)d_in[13];
    const float* down_b = (const float*)d_in[14];
    const float* lnf_s  = (const float*)d_in[15];
    const float* out_w  = (const float*)d_in[16];
    const float* out_b  = (const float*)d_in[17];
    float* out = (float*)d_out;

    char* ws = (char*)d_ws;
    float* xa = (float*)ws;                        ws += (size_t)M_ * HID * 4;
    float* xb = (float*)ws;                        ws += (size_t)M_ * HID * 4;
    __hip_bfloat16* t1b = (__hip_bfloat16*)ws;     ws += (size_t)M_ * HID * 2;
    __hip_bfloat16* t2b = (__hip_bfloat16*)ws;     ws += (size_t)M_ * HID4 * 2;
    __hip_bfloat16* upT  = (__hip_bfloat16*)ws;    ws += (size_t)NBLK * HID4 * HID * 2;
    __hip_bfloat16* dnT  = (__hip_bfloat16*)ws;    ws += (size_t)NBLK * HID * HID4 * 2;
    __hip_bfloat16* outT = (__hip_bfloat16*)ws;    ws += (size_t)OUTP * HID * 2;

    tcvt_kernel<<<dim3(HID4 / 32, HID / 32, NBLK), 256, 0, stream>>>(
        up_w, upT, HID, HID4, HID4);
    tcvt_kernel<<<dim3(HID / 32, HID4 / 32, NBLK), 256, 0, stream>>>(
        down_w, dnT, HID4, HID, HID);
    tcvt_kernel<<<dim3(OUTP / 32, HID / 32, 1), 256, 0, stream>>>(
        out_w, outT, HID, OUT_, OUTP);

    patch_kernel<<<M_, 256, 0, stream>>>(fg, qf, pos, in_w, in_b, xa);

    float* xc = xa;
    float* xn = xb;
    for (int b = 0; b < NBLK; ++b) {
        fused_dw_kernel<<<dim3(4, N_), 512, 0, stream>>>(
            xc, xn, t1b, ln1_s + b * HID, ln2_s + b * HID,
            dw1_w + b * 3 * HID4, dw1_b + b * HID4,
            dw2_w + b * 3 * HID4, dw2_b + b * HID4);
        // up: [2048,512] @ [512,2048] -> gelu -> bf16 t2b  (1024 blocks, 64^2, swizzled)
        gemm_tile<64, 64, 2, 2, 1, 1, 1><<<dim3(HID4 / 64, M_ / 64), 256, 0, stream>>>(
            t1b, upT + (size_t)b * HID4 * HID, up_b + b * HID4, nullptr, t2b,
            HID, HID4, HID4);
        // down: [2048,2048] @ [2048,512] -> += xn (fp32)   (256 blocks, split-K, swizzled)
        gemm_tile<64, 64, 2, 2, 2, 2, 1><<<dim3(HID / 64, M_ / 64), 512, 0, stream>>>(
            t2b, dnT + (size_t)b * HID * HID4, down_b + b * HID, xn, nullptr,
            HID4, HID, HID);
        float* tmp = xc; xc = xn; xn = tmp;
    }

    ln_kernel<<<M_ / 4, 256, 0, stream>>>(xc, lnf_s, t1b);
    gemm_tile<64, 64, 2, 2, 1, 0, 0><<<dim3(OUTP / 64, M_ / 64), 256, 0, stream>>>(
        t1b, outT, out_b, out, nullptr, HID, OUT_, OUT_);
}

// Round 9
// 607.121 us; speedup vs baseline: 1.1463x; 1.0096x over previous
//
#include <hip/hip_runtime.h>
#include <hip/hip_bf16.h>

#define N_    64
#define T_    32
#define H_    64
#define W_    64
#define C_    256
#define HID   512
#define HID4  2048
#define NBLK  12
#define P_    7
#define OUT_  388
#define OUTP  448      // OUT_ padded to 64
#define CIN   51
#define M_    (N_*T_)   // 2048

typedef __attribute__((ext_vector_type(4))) float f32x4;
typedef __attribute__((ext_vector_type(8))) short bf16x8;

__device__ __forceinline__ float gelu_f(float x) {
    float x3 = x * x * x;
    return 0.5f * x * (1.f + tanhf(0.7978845608028654f * (x + 0.044715f * x3)));
}

__device__ __forceinline__ void gload_lds16(const void* g, void* l) {
    __builtin_amdgcn_global_load_lds(
        (const __attribute__((address_space(1))) void*)g,
        (__attribute__((address_space(3))) void*)l, 16, 0, 0);
}

// ---------------------------------------------------------------------------
// Patch extraction + input projection fused (unchanged)
// ---------------------------------------------------------------------------
__global__ __launch_bounds__(256) void patch_kernel(
    const float* __restrict__ fg, const float* __restrict__ qf,
    const float* __restrict__ pos, const float* __restrict__ in_w,
    const float* __restrict__ in_b, float* __restrict__ x) {
    __shared__ float4 q[64];
    __shared__ float g[8][8];
    __shared__ float xrow[CIN];
    int m = blockIdx.x;
    int n = m >> 5;
    int t = m & (T_ - 1);
    int tid = threadIdx.x, wid = tid >> 6, lane = tid & 63;
    if (tid < 64) q[tid] = *(const float4*)&qf[n * C_ + tid * 4];
    __syncthreads();
    float posy = pos[m * 2 + 0];
    float posx = pos[m * 2 + 1];
    float py = posy + 2.5f;
    float px = posx + 2.5f;
    int iy = (int)floorf(py), ix = (int)floorf(px);
    float fy = py - (float)iy, fx = px - (float)ix;
    float4 qv = q[lane];
    #pragma unroll
    for (int i = 0; i < 16; ++i) {
        int idx = wid * 16 + i;
        int a = idx >> 3, b = idx & 7;
        int y = iy + a - 6, xc = ix + b - 6;
        float partial = 0.f;
        if (y >= 0 && y < H_ && xc >= 0 && xc < W_) {
            const float4* fp = (const float4*)&fg[(((t * H_ + y) * W_) + xc) * C_];
            float4 v = fp[lane];
            partial = v.x * qv.x + v.y * qv.y + v.z * qv.z + v.w * qv.w;
        }
        #pragma unroll
        for (int o2 = 32; o2; o2 >>= 1) partial += __shfl_xor(partial, o2);
        if (lane == 0) g[a][b] = partial;
    }
    __syncthreads();
    if (tid < 49) {
        int p = tid / 7, qq = tid % 7;
        xrow[tid] = (1.f - fy) * (1.f - fx) * g[p][qq]
                  + (1.f - fy) * fx         * g[p][qq + 1]
                  + fy         * (1.f - fx) * g[p + 1][qq]
                  + fy         * fx         * g[p + 1][qq + 1];
    } else if (tid == 49) {
        xrow[49] = posy * (1.f / 64.f);
    } else if (tid == 50) {
        xrow[50] = posx * (1.f / 64.f);
    }
    __syncthreads();
    float acc0 = in_b[tid], acc1 = in_b[tid + 256];
    #pragma unroll
    for (int c = 0; c < CIN; ++c) {
        float rv = xrow[c];
        acc0 += rv * in_w[c * HID + tid];
        acc1 += rv * in_w[c * HID + tid + 256];
    }
    x[m * HID + tid] = acc0;
    x[m * HID + tid + 256] = acc1;
}

// ---------------------------------------------------------------------------
// Fully fused depthwise residual block + ln2.
// ln2 output now written in chunk-major layout t1T[c][M_][8], c = j>>3.
// ---------------------------------------------------------------------------
__global__ __launch_bounds__(512) void fused_dw_kernel(
    const float* __restrict__ xin, float* __restrict__ xout,
    __hip_bfloat16* __restrict__ t1T,
    const float* __restrict__ ln1s, const float* __restrict__ ln2s,
    const float* __restrict__ w1, const float* __restrict__ b1,
    const float* __restrict__ w2, const float* __restrict__ b2) {
    __shared__ float2 part[12][8];
    int n = blockIdx.y;
    int t0 = blockIdx.x * 8;
    int j = threadIdx.x;
    int lane = j & 63, wave = j >> 6;

    float xv[12];
    #pragma unroll
    for (int tt = 0; tt < 12; ++tt) {
        int t = t0 - 2 + tt;
        xv[tt] = (t >= 0 && t < T_) ? xin[(n * T_ + t) * HID + j] : 0.f;
    }
    #pragma unroll
    for (int tt = 0; tt < 12; ++tt) {
        float s = xv[tt], q = xv[tt] * xv[tt];
        #pragma unroll
        for (int o = 32; o; o >>= 1) { s += __shfl_xor(s, o); q += __shfl_xor(q, o); }
        if (lane == 0) part[tt][wave] = make_float2(s, q);
    }
    __syncthreads();
    float s1v = ln1s[j];
    float xl[12];
    #pragma unroll
    for (int tt = 0; tt < 12; ++tt) {
        int t = t0 - 2 + tt;
        if (t >= 0 && t < T_) {
            float s = 0.f, q = 0.f;
            #pragma unroll
            for (int w = 0; w < 8; ++w) { float2 p = part[tt][w]; s += p.x; q += p.y; }
            float mean = s * (1.f / HID);
            float var  = q * (1.f / HID) - mean * mean;
            xl[tt] = (xv[tt] - mean) * rsqrtf(var + 1e-5f) * s1v;
        } else xl[tt] = 0.f;
    }
    float w1a[12], w2a[12], b1a[4];
    #pragma unroll
    for (int r = 0; r < 3; ++r) {
        *(float4*)&w1a[r * 4] = *(const float4*)&w1[r * HID4 + 4 * j];
        *(float4*)&w2a[r * 4] = *(const float4*)&w2[r * HID4 + 4 * j];
    }
    *(float4*)&b1a[0] = *(const float4*)&b1[4 * j];
    float4 b2v = *(const float4*)&b2[4 * j];
    float h[8];
    float b2sum = b2v.x + b2v.y + b2v.z + b2v.w;
    #pragma unroll
    for (int i = 0; i < 8; ++i) h[i] = b2sum;
    #pragma unroll
    for (int k = 0; k < 4; ++k) {
        float gk[10];
        #pragma unroll
        for (int idx = 0; idx < 10; ++idx) {
            int tp = t0 - 1 + idx;
            if (tp >= 0 && tp < T_) {
                float a = b1a[k] + w1a[0 * 4 + k] * xl[idx]
                                 + w1a[1 * 4 + k] * xl[idx + 1]
                                 + w1a[2 * 4 + k] * xl[idx + 2];
                gk[idx] = gelu_f(a);
            } else gk[idx] = 0.f;
        }
        #pragma unroll
        for (int i = 0; i < 8; ++i)
            h[i] += w2a[0 * 4 + k] * gk[i] + w2a[1 * 4 + k] * gk[i + 1]
                  + w2a[2 * 4 + k] * gk[i + 2];
    }
    float xn[8];
    #pragma unroll
    for (int i = 0; i < 8; ++i) xn[i] = xv[i + 2] + h[i];
    __syncthreads();
    #pragma unroll
    for (int i = 0; i < 8; ++i) {
        float s = xn[i], q = xn[i] * xn[i];
        #pragma unroll
        for (int o = 32; o; o >>= 1) { s += __shfl_xor(s, o); q += __shfl_xor(q, o); }
        if (lane == 0) part[i][wave] = make_float2(s, q);
    }
    __syncthreads();
    float s2v = ln2s[j];
    int cbase = j >> 3, csub = j & 7;
    #pragma unroll
    for (int i = 0; i < 8; ++i) {
        float s = 0.f, q = 0.f;
        #pragma unroll
        for (int w = 0; w < 8; ++w) { float2 p = part[i][w]; s += p.x; q += p.y; }
        float mean = s * (1.f / HID);
        float var  = q * (1.f / HID) - mean * mean;
        float rstd = rsqrtf(var + 1e-5f);
        int row = n * T_ + t0 + i;
        xout[row * HID + j] = xn[i];
        t1T[((size_t)cbase * M_ + row) * 8 + csub] =
            __float2bfloat16((xn[i] - mean) * rstd * s2v);
    }
}

// ---------------------------------------------------------------------------
// LayerNorm, chunk-major bf16 output (final LN only)
// ---------------------------------------------------------------------------
__global__ __launch_bounds__(256) void ln_kernel(
    const float* __restrict__ in, const float* __restrict__ s,
    __hip_bfloat16* __restrict__ t1T) {
    int wid = threadIdx.x >> 6, lane = threadIdx.x & 63;
    int row = blockIdx.x * 4 + wid;
    const float* r = in + row * HID + lane * 8;
    float4 v0 = *(const float4*)r;
    float4 v1 = *(const float4*)(r + 4);
    float sum = v0.x + v0.y + v0.z + v0.w + v1.x + v1.y + v1.z + v1.w;
    float sq  = v0.x*v0.x + v0.y*v0.y + v0.z*v0.z + v0.w*v0.w
              + v1.x*v1.x + v1.y*v1.y + v1.z*v1.z + v1.w*v1.w;
    #pragma unroll
    for (int o = 32; o; o >>= 1) { sum += __shfl_xor(sum, o); sq += __shfl_xor(sq, o); }
    float mean = sum * (1.f / HID);
    float var  = sq * (1.f / HID) - mean * mean;
    float rstd = rsqrtf(var + 1e-5f);
    const float* sp = s + lane * 8;
    float4 s0 = *(const float4*)sp;
    float4 s1 = *(const float4*)(sp + 4);
    float o[8];
    o[0] = (v0.x - mean) * rstd * s0.x; o[1] = (v0.y - mean) * rstd * s0.y;
    o[2] = (v0.z - mean) * rstd * s0.z; o[3] = (v0.w - mean) * rstd * s0.w;
    o[4] = (v1.x - mean) * rstd * s1.x; o[5] = (v1.y - mean) * rstd * s1.y;
    o[6] = (v1.z - mean) * rstd * s1.z; o[7] = (v1.w - mean) * rstd * s1.w;
    alignas(16) __hip_bfloat16 tmp[8];
    #pragma unroll
    for (int i = 0; i < 8; ++i) tmp[i] = __float2bfloat16(o[i]);
    *(bf16x8*)&t1T[((size_t)lane * M_ + row) * 8] = *(bf16x8*)tmp;
}

// ---------------------------------------------------------------------------
// Transpose + fp32 -> bf16 convert (weights, unchanged)
// ---------------------------------------------------------------------------
__global__ __launch_bounds__(256) void tcvt_kernel(
    const float* __restrict__ src, __hip_bfloat16* __restrict__ dst,
    int R, int C, int Cpad) {
    __shared__ float tile[32][33];
    size_t zb = blockIdx.z;
    src += zb * (size_t)R * C;
    dst += zb * (size_t)Cpad * R;
    int c0 = blockIdx.x * 32, r0 = blockIdx.y * 32;
    int tx = threadIdx.x & 31, ty = threadIdx.x >> 5;
    #pragma unroll
    for (int i = 0; i < 4; ++i) {
        int r = r0 + ty + i * 8, c = c0 + tx;
        tile[ty + i * 8][tx] = (c < C) ? src[(size_t)r * C + c] : 0.f;
    }
    __syncthreads();
    #pragma unroll
    for (int i = 0; i < 4; ++i) {
        int c = c0 + ty + i * 8, r = r0 + tx;
        dst[(size_t)c * R + r] = __float2bfloat16(tile[tx][ty + i * 8]);
    }
}

// ---------------------------------------------------------------------------
// Reg-A bf16 MFMA GEMM for K=512: A held fully in registers (chunk-major
// t1T layout), B staged in LDS (double-buffered, XOR-swizzled). 4 waves
// stacked on M (16 rows each), FN=4 -> 64x64 tile per block.
// EPI 0: bias, fp32 store guarded col<Nstore (ldc=Nstore)
// EPI 1: bias+gelu, bf16 store (ldc=ldN)
// ---------------------------------------------------------------------------
template <int EPI, int SWZ>
__global__ __launch_bounds__(256, 4) void gemm_regA(
    const __hip_bfloat16* __restrict__ At,   // [64][M_][8]
    const __hip_bfloat16* __restrict__ Bt,   // [N][512]
    const float* __restrict__ bias, float* __restrict__ Cf,
    __hip_bfloat16* __restrict__ Cb, int ldN, int Nstore) {
    constexpr int K = 512;
    __shared__ alignas(16) __hip_bfloat16 Bs[2][64 * 64];
    int tid = threadIdx.x;
    int lane = tid & 63, w = tid >> 6;

    int row0, col0;
    if (SWZ) {
        int bid = blockIdx.y * gridDim.x + blockIdx.x;
        int chunk = gridDim.y >> 3;
        int xcd = bid & 7;
        int i = bid >> 3;
        row0 = (xcd * chunk + (i % chunk)) * 64;
        col0 = (i / chunk) * 64;
    } else {
        row0 = blockIdx.y * 64;
        col0 = blockIdx.x * 64;
    }

    // A: 16 k-chunks of 8 bf16 per lane, fully coalesced (chunk-major layout)
    int sub = lane >> 4;                 // 0..3
    int arow = row0 + w * 16 + (lane & 15);
    bf16x8 areg[16];
    #pragma unroll
    for (int kb = 0; kb < 16; ++kb) {
        int c = kb * 4 + sub;
        areg[kb] = *(const bf16x8*)&At[((size_t)c * M_ + arow) * 8];
    }

    int rI = lane >> 3;   // row within one staging instr (0..7)
    int cp = lane & 7;    // 16B chunk slot of a 128B row
    auto stageB = [&](int buf, int k0) {
        #pragma unroll
        for (int s = 0; s < 2; ++s) {
            int rbase = w * 16 + s * 8;
            int row = rbase + rI;
            int corig = cp ^ (row & 7);
            gload_lds16(Bt + (size_t)(col0 + row) * K + k0 + corig * 8,
                        (char*)Bs[buf] + rbase * 128);
        }
    };

    f32x4 acc[4];
    #pragma unroll
    for (int n = 0; n < 4; ++n) acc[n] = (f32x4){0.f, 0.f, 0.f, 0.f};

    stageB(0, 0);
    #pragma unroll
    for (int step = 0; step < 8; ++step) {
        int cur = step & 1;
        __builtin_amdgcn_s_barrier();
        if (step < 7) {
            stageB(cur ^ 1, (step + 1) * 64);
            asm volatile("s_waitcnt vmcnt(2)" ::: "memory");
        } else {
            asm volatile("s_waitcnt vmcnt(0)" ::: "memory");
        }
        __builtin_amdgcn_sched_barrier(0);
        __builtin_amdgcn_s_barrier();
        __builtin_amdgcn_sched_barrier(0);
        #pragma unroll
        for (int kk = 0; kk < 2; ++kk) {
            bf16x8 bfr[4];
            #pragma unroll
            for (int n = 0; n < 4; ++n) {
                int row = n * 16 + (lane & 15);
                int chunk = (kk * 4 + sub) ^ (row & 7);
                bfr[n] = *(const bf16x8*)((const char*)Bs[cur] + row * 128 + chunk * 16);
            }
            __builtin_amdgcn_s_setprio(1);
            #pragma unroll
            for (int n = 0; n < 4; ++n)
                acc[n] = __builtin_amdgcn_mfma_f32_16x16x32_bf16(
                    areg[step * 2 + kk], bfr[n], acc[n], 0, 0, 0);
            __builtin_amdgcn_s_setprio(0);
        }
    }

    int cr = (lane >> 4) * 4;
    int cc = lane & 15;
    #pragma unroll
    for (int n = 0; n < 4; ++n) {
        #pragma unroll
        for (int j = 0; j < 4; ++j) {
            int row = row0 + w * 16 + cr + j;
            int col = col0 + n * 16 + cc;
            float v = acc[n][j];
            if (EPI == 0) {
                if (col < Nstore)
                    Cf[(size_t)row * Nstore + col] = v + bias[col];
            } else {
                v = gelu_f(v + bias[col]);
                Cb[(size_t)row * ldN + col] = __float2bfloat16(v);
            }
        }
    }
}

// ---------------------------------------------------------------------------
// Down-GEMM: 64x64 tile, split-K (KG=2), 2-buffer LDS, counted vmcnt,
// XCD-ownership swizzle. C[M,N] = A[M,K] @ Bt[N,K]^T + bias + residual (fp32).
// (unchanged from R8)
// ---------------------------------------------------------------------------
__global__ __launch_bounds__(512) void gemm_down(
    const __hip_bfloat16* __restrict__ A, const __hip_bfloat16* __restrict__ Bt,
    const float* __restrict__ bias, float* __restrict__ Cf,
    int K, int ldN) {
    __shared__ alignas(16) __hip_bfloat16 As[2][2][64 * 64];
    __shared__ alignas(16) __hip_bfloat16 Bs[2][2][64 * 64];
    int tid = threadIdx.x;
    int lane = tid & 63, wave = tid >> 6;
    int g = wave >> 2;
    int w4 = wave & 3;
    int wr = w4 >> 1, wc = w4 & 1;

    int bid = blockIdx.y * gridDim.x + blockIdx.x;
    int chunk = gridDim.y >> 3;
    int xcd = bid & 7;
    int i = bid >> 3;
    int row0 = (xcd * chunk + (i % chunk)) * 64;
    int col0 = (i / chunk) * 64;

    int Kg = K / 2;
    int kbase = g * Kg;

    f32x4 acc[2][2];
    #pragma unroll
    for (int m = 0; m < 2; ++m)
        #pragma unroll
        for (int n = 0; n < 2; ++n)
            acc[m][n] = (f32x4){0.f, 0.f, 0.f, 0.f};

    int rI = lane >> 3;
    int cp = lane & 7;

    auto stage = [&](int buf, int k0) {
        #pragma unroll
        for (int s = 0; s < 2; ++s) {
            int rbase = w4 * 16 + s * 8;
            int row = rbase + rI;
            int corig = cp ^ (row & 7);
            gload_lds16(A + (size_t)(row0 + row) * K + kbase + k0 + corig * 8,
                        (char*)As[g][buf] + rbase * 128);
        }
        #pragma unroll
        for (int s = 0; s < 2; ++s) {
            int rbase = w4 * 16 + s * 8;
            int row = rbase + rI;
            int corig = cp ^ (row & 7);
            gload_lds16(Bt + (size_t)(col0 + row) * K + kbase + k0 + corig * 8,
                        (char*)Bs[g][buf] + rbase * 128);
        }
    };

    int nsteps = Kg >> 6;
    stage(0, 0);
    for (int step = 0; step < nsteps; ++step) {
        int cur = step & 1;
        __builtin_amdgcn_s_barrier();
        if (step + 1 < nsteps) {
            stage(cur ^ 1, (step + 1) * 64);
            asm volatile("s_waitcnt vmcnt(4)" ::: "memory");
        } else {
            asm volatile("s_waitcnt vmcnt(0)" ::: "memory");
        }
        __builtin_amdgcn_sched_barrier(0);
        __builtin_amdgcn_s_barrier();
        __builtin_amdgcn_sched_barrier(0);
        #pragma unroll
        for (int kk = 0; kk < 2; ++kk) {
            bf16x8 af[2], bfr[2];
            #pragma unroll
            for (int m = 0; m < 2; ++m) {
                int row = wr * 32 + m * 16 + (lane & 15);
                int chunk2 = (kk * 4 + (lane >> 4)) ^ (row & 7);
                af[m] = *(const bf16x8*)((const char*)As[g][cur] + row * 128 + chunk2 * 16);
            }
            #pragma unroll
            for (int n = 0; n < 2; ++n) {
                int row = wc * 32 + n * 16 + (lane & 15);
                int chunk2 = (kk * 4 + (lane >> 4)) ^ (row & 7);
                bfr[n] = *(const bf16x8*)((const char*)Bs[g][cur] + row * 128 + chunk2 * 16);
            }
            __builtin_amdgcn_s_setprio(1);
            #pragma unroll
            for (int m = 0; m < 2; ++m)
                #pragma unroll
                for (int n = 0; n < 2; ++n)
                    acc[m][n] = __builtin_amdgcn_mfma_f32_16x16x32_bf16(
                        af[m], bfr[n], acc[m][n], 0, 0, 0);
            __builtin_amdgcn_s_setprio(0);
        }
    }

    int cr = (lane >> 4) * 4;
    int cc = lane & 15;

    float* scratch = (float*)&As[0][0][0];
    __syncthreads();
    if (g == 1) {
        #pragma unroll
        for (int m = 0; m < 2; ++m)
            #pragma unroll
            for (int n = 0; n < 2; ++n)
                #pragma unroll
                for (int j = 0; j < 4; ++j)
                    scratch[(wr * 32 + m * 16 + cr + j) * 64 +
                            wc * 32 + n * 16 + cc] = acc[m][n][j];
    }
    __syncthreads();
    if (g == 1) return;
    #pragma unroll
    for (int m = 0; m < 2; ++m) {
        #pragma unroll
        for (int n = 0; n < 2; ++n) {
            #pragma unroll
            for (int j = 0; j < 4; ++j) {
                int row = row0 + wr * 32 + m * 16 + cr + j;
                int col = col0 + wc * 32 + n * 16 + cc;
                float v = acc[m][n][j] +
                          scratch[(wr * 32 + m * 16 + cr + j) * 64 +
                                  wc * 32 + n * 16 + cc];
                Cf[(size_t)row * ldN + col] += v + bias[col];
            }
        }
    }
}

// ---------------------------------------------------------------------------
extern "C" void kernel_launch(void* const* d_in, const int* in_sizes, int n_in,
                              void* d_out, int out_size, void* d_ws, size_t ws_size,
                              hipStream_t stream) {
    const float* fg     = (const float*)d_in[0];
    const float* qf     = (const float*)d_in[1];
    const float* pos    = (const float*)d_in[2];
    const float* in_w   = (const float*)d_in[3];
    const float* in_b   = (const float*)d_in[4];
    const float* dw1_w  = (const float*)d_in[5];
    const float* dw1_b  = (const float*)d_in[6];
    const float* dw2_w  = (const float*)d_in[7];
    const float* dw2_b  = (const float*)d_in[8];
    const float* ln1_s  = (const float*)d_in[9];
    const float* ln2_s  = (const float*)d_in[10];
    const float* up_w   = (const float*)d_in[11];
    const float* up_b   = (const float*)d_in[12];
    const float* down_w = (const float*)d_in[13];
    const float* down_b = (const float*)d_in[14];
    const float* lnf_s  = (const float*)d_in[15];
    const float* out_w  = (const float*)d_in[16];
    const float* out_b  = (const float*)d_in[17];
    float* out = (float*)d_out;

    char* ws = (char*)d_ws;
    float* xa = (float*)ws;                        ws += (size_t)M_ * HID * 4;
    float* xb = (float*)ws;                        ws += (size_t)M_ * HID * 4;
    __hip_bfloat16* t1T = (__hip_bfloat16*)ws;     ws += (size_t)M_ * HID * 2;
    __hip_bfloat16* t2b = (__hip_bfloat16*)ws;     ws += (size_t)M_ * HID4 * 2;
    __hip_bfloat16* upT  = (__hip_bfloat16*)ws;    ws += (size_t)NBLK * HID4 * HID * 2;
    __hip_bfloat16* dnT  = (__hip_bfloat16*)ws;    ws += (size_t)NBLK * HID * HID4 * 2;
    __hip_bfloat16* outT = (__hip_bfloat16*)ws;    ws += (size_t)OUTP * HID * 2;

    tcvt_kernel<<<dim3(HID4 / 32, HID / 32, NBLK), 256, 0, stream>>>(
        up_w, upT, HID, HID4, HID4);
    tcvt_kernel<<<dim3(HID / 32, HID4 / 32, NBLK), 256, 0, stream>>>(
        down_w, dnT, HID4, HID, HID);
    tcvt_kernel<<<dim3(OUTP / 32, HID / 32, 1), 256, 0, stream>>>(
        out_w, outT, HID, OUT_, OUTP);

    patch_kernel<<<M_, 256, 0, stream>>>(fg, qf, pos, in_w, in_b, xa);

    float* xc = xa;
    float* xn = xb;
    for (int b = 0; b < NBLK; ++b) {
        fused_dw_kernel<<<dim3(4, N_), 512, 0, stream>>>(
            xc, xn, t1T, ln1_s + b * HID, ln2_s + b * HID,
            dw1_w + b * 3 * HID4, dw1_b + b * HID4,
            dw2_w + b * 3 * HID4, dw2_b + b * HID4);
        // up: [2048,512] @ [512,2048] -> gelu -> bf16 t2b (reg-A, 1024 blocks)
        gemm_regA<1, 1><<<dim3(HID4 / 64, M_ / 64), 256, 0, stream>>>(
            t1T, upT + (size_t)b * HID4 * HID, up_b + b * HID4, nullptr, t2b,
            HID4, HID4);
        // down: [2048,2048] @ [2048,512] -> += xn (fp32)  (256 blocks, split-K)
        gemm_down<<<dim3(HID / 64, M_ / 64), 512, 0, stream>>>(
            t2b, dnT + (size_t)b * HID * HID4, down_b + b * HID, xn,
            HID4, HID);
        float* tmp = xc; xc = xn; xn = tmp;
    }

    ln_kernel<<<M_ / 4, 256, 0, stream>>>(xc, lnf_s, t1T);
    gemm_regA<0, 0><<<dim3(OUTP / 64, M_ / 64), 256, 0, stream>>>(
        t1T, outT, out_b, out, nullptr, OUT_, OUT_);
}